// Round 26
// baseline (66.537 us; speedup 1.0000x reference)
//
#include <hip/hip_runtime.h>

using f32x16 = __attribute__((ext_vector_type(16))) float;
using i32x8  = __attribute__((ext_vector_type(8))) int;

constexpr int   N = 8192;
constexpr int   D = 512;
// sqrt((1/T) * log2(e)) folded into the normalized vectors; dot feeds exp2 directly.
constexpr float SCALE_FOLD = 1.6986436f;
constexpr int   CGROUPS = 64;                        // 64 col groups of 128

// Single-instruction 2^x (arg range here is [-2.9, 2.9]).
#if __has_builtin(__builtin_amdgcn_exp2f)
#define EXP2(x) __builtin_amdgcn_exp2f(x)
#else
static __device__ __forceinline__ float EXP2(float x) {
  float r;
  asm("v_exp_f32 %0, %1" : "=v"(r) : "v"(x));
  return r;
}
#endif

static __device__ __forceinline__ void gld16(const unsigned char* g, unsigned char* l) {
  __builtin_amdgcn_global_load_lds(
      (const __attribute__((address_space(1))) void*)g,
      (__attribute__((address_space(3))) void*)l, 16, 0, 0);
}

// One wave per row; rows [0,N) -> out0, [N,2N) -> out1.  f32 -> fp8 e4m3 (OCP).
// Per-row pre-permutation for the GEMM LDS scheme: within each 64B k-tile,
// logical 16B granule g (=k8>>1, half h=k8&1) stored at granule g ^ ((row>>1)&3).
__global__ __launch_bounds__(256) void normalize_kernel(
    const float* __restrict__ in0, const float* __restrict__ in1,
    unsigned char* __restrict__ n0, unsigned char* __restrict__ n1) {
  int gw   = (blockIdx.x * 256 + threadIdx.x) >> 6;
  int lane = threadIdx.x & 63;
  int row  = (gw < N) ? gw : gw - N;
  const float* src = (gw < N) ? in0 + (size_t)row * D : in1 + (size_t)row * D;
  unsigned char* dstrow = (gw < N) ? n0 + (size_t)row * D : n1 + (size_t)row * D;

  const float4* s4 = reinterpret_cast<const float4*>(src) + (size_t)lane * 2;
  float4 v0 = s4[0], v1 = s4[1];
  float ss = v0.x*v0.x + v0.y*v0.y + v0.z*v0.z + v0.w*v0.w
           + v1.x*v1.x + v1.y*v1.y + v1.z*v1.z + v1.w*v1.w;
#pragma unroll
  for (int m = 1; m <= 32; m <<= 1) ss += __shfl_xor(ss, m);
  float s = SCALE_FOLD / fmaxf(sqrtf(ss), 1e-12f);

  int w0 = 0, w1 = 0;
  w0 = __builtin_amdgcn_cvt_pk_fp8_f32(v0.x * s, v0.y * s, w0, false);
  w0 = __builtin_amdgcn_cvt_pk_fp8_f32(v0.z * s, v0.w * s, w0, true);
  w1 = __builtin_amdgcn_cvt_pk_fp8_f32(v1.x * s, v1.y * s, w1, false);
  w1 = __builtin_amdgcn_cvt_pk_fp8_f32(v1.z * s, v1.w * s, w1, true);
  int2 o; o.x = w0; o.y = w1;

  const int c  = (row >> 1) & 3;
  const int k8 = lane & 7;                 // logical 8B slot in the 64B k-tile
  const int g  = k8 >> 1, h = k8 & 1;      // 16B granule, 8B half (k-contiguous)
  const int off = (lane >> 3) * 64 + ((g ^ c) * 16) + h * 8;
  *reinterpret_cast<int2*>(dstrow + off) = o;
}

// MX-fp8 fused GEMM: 128x128 tile, 4 waves, BK=64 (8 K-steps), 2-deep LDS
// (4 blocks/CU with the (256,4) reg cap), counted vmcnt(4) gates; tile kk+2
// staged into buf kk&1 AFTER a post-MFMA barrier (all waves' reads done).
// SWAPPED operands: mfma(b, a) -> lane = output row, regs = cols.
// L2-blocked XCD chunking: each XCD owns a 16-rowtile x 32-colgrp chunk
// (A 1 MB + B 2 MB < 4 MB per-XCD L2) so staged loads are L2 hits.
__global__ __launch_bounds__(256, 4) void ntxent_main(
    const unsigned char* __restrict__ n0, const unsigned char* __restrict__ n1,
    const int* __restrict__ labels,
    float* __restrict__ part_pos, float* __restrict__ part_all) {
  __shared__ unsigned char As[2][128 * 64];   // 16 KiB
  __shared__ unsigned char Bs[2][128 * 64];   // 16 KiB
  __shared__ float redS[256];                 // 1 KiB
  __shared__ int   labC[128];                 // 0.5 KiB: col labels of this colgrp

  const int t    = threadIdx.x;
  const int lane = t & 63;
  const int wid  = t >> 6;
  const int l31  = lane & 31;
  const int hi   = lane >> 5;   // k-half of frags; col-half of D regs
  const int wr   = wid >> 1;    // 0/1 : rows wr*64..+64
  const int wc   = wid & 1;     // 0/1 : cols wc*64..+64

  // L2-blocked XCD chunking (bijective): xcd = bid&7 owns rowtiles
  // [ (xcd>>1)*16 .. +16 ) x colgrps [ (xcd&1)*32 .. +32 ).
  const int xcd = blockIdx.x & 7;
  const int c   = blockIdx.x >> 3;           // 0..511 within chunk
  const int rowtile = (xcd >> 1) * 16 + (c & 15);
  const int colgrp  = (xcd & 1) * 32 + (c >> 4);
  const int rowbase = rowtile * 128;
  const int colb    = colgrp * 128;

  if (t < 128) labC[t] = labels[colb + t];

  // ---- staging (plain linear; global is pre-permuted by normalize) ----
  const unsigned char* gA = n0 + (size_t)(rowbase + (t >> 2)) * D + (t & 3) * 16;
  const unsigned char* gB = n1 + (size_t)(colb    + (t >> 2)) * D + (t & 3) * 16;
  unsigned char* const lA = &As[0][0] + (t >> 2) * 64 + (t & 3) * 16;
  unsigned char* const lB = &Bs[0][0] + (t >> 2) * 64 + (t & 3) * 16;

#define STAGE(st, sb) do { \
    const unsigned char* _ga = gA + (st) * 64; \
    const unsigned char* _gb = gB + (st) * 64; \
    unsigned char* _la = lA + (sb) * 8192; \
    unsigned char* _lb = lB + (sb) * 8192; \
    gld16(_ga, _la); gld16(_ga + (size_t)64 * D, _la + 4096); \
    gld16(_gb, _lb); gld16(_gb + (size_t)64 * D, _lb + 4096); \
  } while (0)

  // ---- ds_read byte offsets: frag row tr, logical granule 2*hi (+1 at ^16) ----
  int aoff[2], boff[2];
#pragma unroll
  for (int mi = 0; mi < 2; ++mi) {
    int tr = wr * 64 + mi * 32 + l31;
    aoff[mi] = tr * 64 + (((hi << 1) ^ ((tr >> 1) & 3)) << 4);
  }
#pragma unroll
  for (int ji = 0; ji < 2; ++ji) {
    int tc = wc * 64 + ji * 32 + l31;
    boff[ji] = tc * 64 + (((hi << 1) ^ ((tc >> 1) & 3)) << 4);
  }

#define GATE4 asm volatile("s_waitcnt vmcnt(4)\n\ts_barrier" ::: "memory")
#define GATE0 asm volatile("s_waitcnt vmcnt(0)\n\ts_barrier" ::: "memory")
#define BARP  asm volatile("s_barrier" ::: "memory")
#define EBAR  asm volatile("s_waitcnt lgkmcnt(0)\n\ts_barrier" ::: "memory")

  const int sc1 = 0x7f7f7f7f;   // e8m0 scale = 1.0 in all byte lanes

  f32x16 acc[2][2];             // acc[ji][mi]: lane=row i, regs=col j
#pragma unroll
  for (int ji = 0; ji < 2; ++ji)
#pragma unroll
    for (int mi = 0; mi < 2; ++mi) acc[ji][mi] = 0.f;

  // prologue: stage k-tiles 0,1 into bufs 0,1  (8 loads outstanding)
  STAGE(0, 0);
  STAGE(1, 1);

#pragma unroll
  for (int kk = 0; kk < 8; ++kk) {
    // drain own oldest k-tile's 4 loads; keep next tile's 4 in flight
    if (kk < 7) { GATE4; } else { GATE0; }

    const unsigned char* bufA = &As[kk & 1][0];
    const unsigned char* bufB = &Bs[kk & 1][0];
    i32x8 a[2], b[2];
#pragma unroll
    for (int mi = 0; mi < 2; ++mi) {   // read straight into the operand halves
      int4* pa = (int4*)&a[mi];
      pa[0] = *(const int4*)&bufA[aoff[mi]];
      pa[1] = *(const int4*)&bufA[aoff[mi] ^ 16];
    }
#pragma unroll
    for (int ji = 0; ji < 2; ++ji) {
      int4* pb = (int4*)&b[ji];
      pb[0] = *(const int4*)&bufB[boff[ji]];
      pb[1] = *(const int4*)&bufB[boff[ji] ^ 16];
    }

#pragma unroll
    for (int ji = 0; ji < 2; ++ji)
#pragma unroll
      for (int mi = 0; mi < 2; ++mi)
        acc[ji][mi] = __builtin_amdgcn_mfma_scale_f32_32x32x64_f8f6f4(
            b[ji], a[mi], acc[ji][mi], 0, 0, 0, sc1, 0, sc1);

    // After this barrier every wave has finished reading buf kk&1
    // (compiler-inserted lgkmcnt before MFMA) -> safe to overwrite it.
    if (kk < 6) { BARP; STAGE(kk + 2, kk & 1); }
  }

  // ---- epilogue: lane-local row reduction (single-instruction v_exp_f32) ----
  // D[j][i]: lane l31 = row i (within mi-frag), reg r -> col
  // j = wc*64 + ji*32 + (r&3) + 8*(r>>2) + 4*hi.
  int labi[2];
#pragma unroll
  for (int mi = 0; mi < 2; ++mi)
    labi[mi] = labels[rowbase + wr * 64 + mi * 32 + l31];

  float asum[2] = {0.f, 0.f};
  float psum[2] = {0.f, 0.f};
#pragma unroll
  for (int ji = 0; ji < 2; ++ji)
#pragma unroll
    for (int rq = 0; rq < 4; ++rq) {
      const int4 labj = *(const int4*)&labC[wc * 64 + ji * 32 + rq * 8 + 4 * hi];
#pragma unroll
      for (int mi = 0; mi < 2; ++mi)
#pragma unroll
        for (int rr = 0; rr < 4; ++rr) {
          float e = EXP2(acc[ji][mi][rq * 4 + rr]);
          asum[mi] += e;
          int lb = (rr == 0) ? labj.x : (rr == 1) ? labj.y : (rr == 2) ? labj.z : labj.w;
          if (lb == labi[mi]) psum[mi] += e;
        }
    }

  // fold the two col-halves (lane l <-> l+32 hold same row, different cols)
#pragma unroll
  for (int mi = 0; mi < 2; ++mi) {
    asum[mi] += __shfl_xor(asum[mi], 32);
    psum[mi] += __shfl_xor(psum[mi], 32);
  }

  // cross-wave combine over wc
  float* redSa = redS;          // [128]
  float* redSp = redS + 128;    // [128]
  if (wc == 1 && hi == 0) {
#pragma unroll
    for (int mi = 0; mi < 2; ++mi) {
      redSa[wr * 64 + mi * 32 + l31] = asum[mi];
      redSp[wr * 64 + mi * 32 + l31] = psum[mi];
    }
  }
  EBAR;
  if (wc == 0 && hi == 0) {
#pragma unroll
    for (int mi = 0; mi < 2; ++mi) {
      const int idx = wr * 64 + mi * 32 + l31;
      const int row = rowbase + idx;
      part_all[(size_t)colgrp * N + row] = asum[mi] + redSa[idx];
      part_pos[(size_t)colgrp * N + row] = psum[mi] + redSp[idx];
    }
  }
}

// Fused reduction: per-row log(all)-log(pos), block tree-reduce, then the
// LAST block (device-scope atomic counter, memset to 0 in-stream each call)
// sums the 32 block partials in fixed order and writes the loss. Deterministic.
__global__ __launch_bounds__(256) void loss_reduce(
    const float* __restrict__ part_pos, const float* __restrict__ part_all,
    float* __restrict__ blocksum, unsigned* __restrict__ counter,
    float* __restrict__ out) {
  const int i = blockIdx.x * 256 + threadIdx.x;
  float a = 0.f, p = 0.f;
#pragma unroll 4
  for (int cs = 0; cs < CGROUPS; ++cs) {
    a += part_all[(size_t)cs * N + i];
    p += part_pos[(size_t)cs * N + i];
  }
  float s = logf(a) - logf(p);
  __shared__ float red[256];
  __shared__ unsigned done;
  red[threadIdx.x] = s;
  __syncthreads();
  for (int off = 128; off > 0; off >>= 1) {
    if (threadIdx.x < off) red[threadIdx.x] += red[threadIdx.x + off];
    __syncthreads();
  }
  if (threadIdx.x == 0) {
    blocksum[blockIdx.x] = red[0];
    __threadfence();
    done = atomicAdd(counter, 1u);
  }
  __syncthreads();
  if (done == gridDim.x - 1) {        // last block finishes the reduction
    __threadfence();
    if (threadIdx.x < 64) {
      float v = (threadIdx.x < N / 256) ? blocksum[threadIdx.x] : 0.f;
#pragma unroll
      for (int m = 1; m <= 32; m <<= 1) v += __shfl_xor(v, m);
      if (threadIdx.x == 0) out[0] = v / (float)N;
    }
  }
}

extern "C" void kernel_launch(void* const* d_in, const int* in_sizes, int n_in,
                              void* d_out, int out_size, void* d_ws, size_t ws_size,
                              hipStream_t stream) {
  const float* out0   = (const float*)d_in[0];
  const float* out1   = (const float*)d_in[1];
  const int*   labels = (const int*)d_in[2];
  float*       out    = (float*)d_out;

  char* ws = (char*)d_ws;
  unsigned char* n0 = (unsigned char*)ws;                            // 4 MB
  unsigned char* n1 = (unsigned char*)(ws + (size_t)N * D);          // 4 MB
  float* part_pos = (float*)(ws + (size_t)2 * N * D);                // 2 MB
  float* part_all = part_pos + (size_t)CGROUPS * N;                  // 2 MB
  float* blocksum = part_all + (size_t)CGROUPS * N;                  // 128 B
  unsigned* counter = (unsigned*)(blocksum + 32);                    // 4 B

  hipMemsetAsync(counter, 0, sizeof(unsigned), stream);
  hipLaunchKernelGGL(normalize_kernel, dim3(2 * N / 4), dim3(256), 0, stream,
                     out0, out1, n0, n1);
  hipLaunchKernelGGL(ntxent_main, dim3(4096), dim3(256), 0, stream,
                     n0, n1, labels, part_pos, part_all);
  hipLaunchKernelGGL(loss_reduce, dim3(N / 256), dim3(256), 0, stream,
                     part_pos, part_all, blocksum, counter, out);
}

// Round 27
// 59.943 us; speedup vs baseline: 1.1100x; 1.1100x over previous
//
#include <hip/hip_runtime.h>

using f32x16 = __attribute__((ext_vector_type(16))) float;
using i32x8  = __attribute__((ext_vector_type(8))) int;

constexpr int   N = 8192;
constexpr int   D = 512;
// sqrt((1/T) * log2(e)) folded into the normalized vectors; dot feeds exp2 directly.
constexpr float SCALE_FOLD = 1.6986436f;
constexpr int   CGROUPS = 64;                        // 64 col groups of 128

// Single-instruction 2^x (arg range here is [-2.9, 2.9]).
#if __has_builtin(__builtin_amdgcn_exp2f)
#define EXP2(x) __builtin_amdgcn_exp2f(x)
#else
static __device__ __forceinline__ float EXP2(float x) {
  float r;
  asm("v_exp_f32 %0, %1" : "=v"(r) : "v"(x));
  return r;
}
#endif

static __device__ __forceinline__ void gld16(const unsigned char* g, unsigned char* l) {
  __builtin_amdgcn_global_load_lds(
      (const __attribute__((address_space(1))) void*)g,
      (__attribute__((address_space(3))) void*)l, 16, 0, 0);
}

// One wave per row; rows [0,N) -> out0, [N,2N) -> out1.  f32 -> fp8 e4m3 (OCP).
// Per-row pre-permutation for the GEMM LDS scheme: within each 64B k-tile,
// logical 16B granule g (=k8>>1, half h=k8&1) stored at granule g ^ ((row>>1)&3).
__global__ __launch_bounds__(256) void normalize_kernel(
    const float* __restrict__ in0, const float* __restrict__ in1,
    unsigned char* __restrict__ n0, unsigned char* __restrict__ n1) {
  int gw   = (blockIdx.x * 256 + threadIdx.x) >> 6;
  int lane = threadIdx.x & 63;
  int row  = (gw < N) ? gw : gw - N;
  const float* src = (gw < N) ? in0 + (size_t)row * D : in1 + (size_t)row * D;
  unsigned char* dstrow = (gw < N) ? n0 + (size_t)row * D : n1 + (size_t)row * D;

  const float4* s4 = reinterpret_cast<const float4*>(src) + (size_t)lane * 2;
  float4 v0 = s4[0], v1 = s4[1];
  float ss = v0.x*v0.x + v0.y*v0.y + v0.z*v0.z + v0.w*v0.w
           + v1.x*v1.x + v1.y*v1.y + v1.z*v1.z + v1.w*v1.w;
#pragma unroll
  for (int m = 1; m <= 32; m <<= 1) ss += __shfl_xor(ss, m);
  float s = SCALE_FOLD / fmaxf(sqrtf(ss), 1e-12f);

  int w0 = 0, w1 = 0;
  w0 = __builtin_amdgcn_cvt_pk_fp8_f32(v0.x * s, v0.y * s, w0, false);
  w0 = __builtin_amdgcn_cvt_pk_fp8_f32(v0.z * s, v0.w * s, w0, true);
  w1 = __builtin_amdgcn_cvt_pk_fp8_f32(v1.x * s, v1.y * s, w1, false);
  w1 = __builtin_amdgcn_cvt_pk_fp8_f32(v1.z * s, v1.w * s, w1, true);
  int2 o; o.x = w0; o.y = w1;

  const int c  = (row >> 1) & 3;
  const int k8 = lane & 7;                 // logical 8B slot in the 64B k-tile
  const int g  = k8 >> 1, h = k8 & 1;      // 16B granule, 8B half (k-contiguous)
  const int off = (lane >> 3) * 64 + ((g ^ c) * 16) + h * 8;
  *reinterpret_cast<int2*>(dstrow + off) = o;
}

// MX-fp8 fused GEMM: 128x128 tile, 4 waves, BK=64 (8 K-steps), 2-deep LDS
// (4 blocks/CU with the (256,4) reg cap), counted vmcnt(4) gates; tile kk+2
// staged into buf kk&1 AFTER a post-MFMA barrier (all waves' reads done).
// SWAPPED operands: mfma(b, a) -> lane = output row, regs = cols.
// L2-blocked XCD chunking: each XCD owns a 16-rowtile x 32-colgrp chunk
// (A 1 MB + B 2 MB < 4 MB per-XCD L2) so staged loads are L2 hits.
__global__ __launch_bounds__(256, 4) void ntxent_main(
    const unsigned char* __restrict__ n0, const unsigned char* __restrict__ n1,
    const int* __restrict__ labels,
    float* __restrict__ part_pos, float* __restrict__ part_all) {
  __shared__ unsigned char As[2][128 * 64];   // 16 KiB
  __shared__ unsigned char Bs[2][128 * 64];   // 16 KiB
  __shared__ float redS[256];                 // 1 KiB
  __shared__ int   labC[128];                 // 0.5 KiB: col labels of this colgrp

  const int t    = threadIdx.x;
  const int lane = t & 63;
  const int wid  = t >> 6;
  const int l31  = lane & 31;
  const int hi   = lane >> 5;   // k-half of frags; col-half of D regs
  const int wr   = wid >> 1;    // 0/1 : rows wr*64..+64
  const int wc   = wid & 1;     // 0/1 : cols wc*64..+64

  // L2-blocked XCD chunking (bijective): xcd = bid&7 owns rowtiles
  // [ (xcd>>1)*16 .. +16 ) x colgrps [ (xcd&1)*32 .. +32 ).
  const int xcd = blockIdx.x & 7;
  const int c   = blockIdx.x >> 3;           // 0..511 within chunk
  const int rowtile = (xcd >> 1) * 16 + (c & 15);
  const int colgrp  = (xcd & 1) * 32 + (c >> 4);
  const int rowbase = rowtile * 128;
  const int colb    = colgrp * 128;

  if (t < 128) labC[t] = labels[colb + t];

  // ---- staging (plain linear; global is pre-permuted by normalize) ----
  const unsigned char* gA = n0 + (size_t)(rowbase + (t >> 2)) * D + (t & 3) * 16;
  const unsigned char* gB = n1 + (size_t)(colb    + (t >> 2)) * D + (t & 3) * 16;
  unsigned char* const lA = &As[0][0] + (t >> 2) * 64 + (t & 3) * 16;
  unsigned char* const lB = &Bs[0][0] + (t >> 2) * 64 + (t & 3) * 16;

#define STAGE(st, sb) do { \
    const unsigned char* _ga = gA + (st) * 64; \
    const unsigned char* _gb = gB + (st) * 64; \
    unsigned char* _la = lA + (sb) * 8192; \
    unsigned char* _lb = lB + (sb) * 8192; \
    gld16(_ga, _la); gld16(_ga + (size_t)64 * D, _la + 4096); \
    gld16(_gb, _lb); gld16(_gb + (size_t)64 * D, _lb + 4096); \
  } while (0)

  // ---- ds_read byte offsets: frag row tr, logical granule 2*hi (+1 at ^16) ----
  int aoff[2], boff[2];
#pragma unroll
  for (int mi = 0; mi < 2; ++mi) {
    int tr = wr * 64 + mi * 32 + l31;
    aoff[mi] = tr * 64 + (((hi << 1) ^ ((tr >> 1) & 3)) << 4);
  }
#pragma unroll
  for (int ji = 0; ji < 2; ++ji) {
    int tc = wc * 64 + ji * 32 + l31;
    boff[ji] = tc * 64 + (((hi << 1) ^ ((tc >> 1) & 3)) << 4);
  }

#define GATE4 asm volatile("s_waitcnt vmcnt(4)\n\ts_barrier" ::: "memory")
#define GATE0 asm volatile("s_waitcnt vmcnt(0)\n\ts_barrier" ::: "memory")
#define BARP  asm volatile("s_barrier" ::: "memory")
#define EBAR  asm volatile("s_waitcnt lgkmcnt(0)\n\ts_barrier" ::: "memory")

  const int sc1 = 0x7f7f7f7f;   // e8m0 scale = 1.0 in all byte lanes

  f32x16 acc[2][2];             // acc[ji][mi]: lane=row i, regs=col j
#pragma unroll
  for (int ji = 0; ji < 2; ++ji)
#pragma unroll
    for (int mi = 0; mi < 2; ++mi) acc[ji][mi] = 0.f;

  // prologue: stage k-tiles 0,1 into bufs 0,1  (8 loads outstanding)
  STAGE(0, 0);
  STAGE(1, 1);

#pragma unroll
  for (int kk = 0; kk < 8; ++kk) {
    // drain own oldest k-tile's 4 loads; keep next tile's 4 in flight
    if (kk < 7) { GATE4; } else { GATE0; }

    const unsigned char* bufA = &As[kk & 1][0];
    const unsigned char* bufB = &Bs[kk & 1][0];
    i32x8 a[2], b[2];
#pragma unroll
    for (int mi = 0; mi < 2; ++mi) {   // read straight into the operand halves
      int4* pa = (int4*)&a[mi];
      pa[0] = *(const int4*)&bufA[aoff[mi]];
      pa[1] = *(const int4*)&bufA[aoff[mi] ^ 16];
    }
#pragma unroll
    for (int ji = 0; ji < 2; ++ji) {
      int4* pb = (int4*)&b[ji];
      pb[0] = *(const int4*)&bufB[boff[ji]];
      pb[1] = *(const int4*)&bufB[boff[ji] ^ 16];
    }

#pragma unroll
    for (int ji = 0; ji < 2; ++ji)
#pragma unroll
      for (int mi = 0; mi < 2; ++mi)
        acc[ji][mi] = __builtin_amdgcn_mfma_scale_f32_32x32x64_f8f6f4(
            b[ji], a[mi], acc[ji][mi], 0, 0, 0, sc1, 0, sc1);

    // After this barrier every wave has finished reading buf kk&1
    // (compiler-inserted lgkmcnt before MFMA) -> safe to overwrite it.
    if (kk < 6) { BARP; STAGE(kk + 2, kk & 1); }
  }

  // ---- epilogue: lane-local row reduction (single-instruction v_exp_f32) ----
  // D[j][i]: lane l31 = row i (within mi-frag), reg r -> col
  // j = wc*64 + ji*32 + (r&3) + 8*(r>>2) + 4*hi.
  int labi[2];
#pragma unroll
  for (int mi = 0; mi < 2; ++mi)
    labi[mi] = labels[rowbase + wr * 64 + mi * 32 + l31];

  float asum[2] = {0.f, 0.f};
  float psum[2] = {0.f, 0.f};
#pragma unroll
  for (int ji = 0; ji < 2; ++ji)
#pragma unroll
    for (int rq = 0; rq < 4; ++rq) {
      const int4 labj = *(const int4*)&labC[wc * 64 + ji * 32 + rq * 8 + 4 * hi];
#pragma unroll
      for (int mi = 0; mi < 2; ++mi)
#pragma unroll
        for (int rr = 0; rr < 4; ++rr) {
          float e = EXP2(acc[ji][mi][rq * 4 + rr]);
          asum[mi] += e;
          int lb = (rr == 0) ? labj.x : (rr == 1) ? labj.y : (rr == 2) ? labj.z : labj.w;
          if (lb == labi[mi]) psum[mi] += e;
        }
    }

  // fold the two col-halves (lane l <-> l+32 hold same row, different cols)
#pragma unroll
  for (int mi = 0; mi < 2; ++mi) {
    asum[mi] += __shfl_xor(asum[mi], 32);
    psum[mi] += __shfl_xor(psum[mi], 32);
  }

  // cross-wave combine over wc
  float* redSa = redS;          // [128]
  float* redSp = redS + 128;    // [128]
  if (wc == 1 && hi == 0) {
#pragma unroll
    for (int mi = 0; mi < 2; ++mi) {
      redSa[wr * 64 + mi * 32 + l31] = asum[mi];
      redSp[wr * 64 + mi * 32 + l31] = psum[mi];
    }
  }
  EBAR;
  if (wc == 0 && hi == 0) {
#pragma unroll
    for (int mi = 0; mi < 2; ++mi) {
      const int idx = wr * 64 + mi * 32 + l31;
      const int row = rowbase + idx;
      part_all[(size_t)colgrp * N + row] = asum[mi] + redSa[idx];
      part_pos[(size_t)colgrp * N + row] = psum[mi] + redSp[idx];
    }
  }
}

// Stage 1: one row per thread, coalesced over cs; per-block tree reduce.
__global__ __launch_bounds__(256) void row_reduce(
    const float* __restrict__ part_pos, const float* __restrict__ part_all,
    float* __restrict__ blocksum) {
  const int i = blockIdx.x * 256 + threadIdx.x;
  float a = 0.f, p = 0.f;
#pragma unroll 4
  for (int cs = 0; cs < CGROUPS; ++cs) {
    a += part_all[(size_t)cs * N + i];
    p += part_pos[(size_t)cs * N + i];
  }
  float s = logf(a) - logf(p);
  __shared__ float red[256];
  red[threadIdx.x] = s;
  __syncthreads();
  for (int off = 128; off > 0; off >>= 1) {
    if (threadIdx.x < off) red[threadIdx.x] += red[threadIdx.x + off];
    __syncthreads();
  }
  if (threadIdx.x == 0) blocksum[blockIdx.x] = red[0];
}

// Stage 2: one wave sums the 32 block partials.
__global__ __launch_bounds__(64) void final_sum(
    const float* __restrict__ blocksum, float* __restrict__ out) {
  float s = (threadIdx.x < N / 256) ? blocksum[threadIdx.x] : 0.f;
#pragma unroll
  for (int m = 1; m <= 32; m <<= 1) s += __shfl_xor(s, m);
  if (threadIdx.x == 0) out[0] = s / (float)N;
}

extern "C" void kernel_launch(void* const* d_in, const int* in_sizes, int n_in,
                              void* d_out, int out_size, void* d_ws, size_t ws_size,
                              hipStream_t stream) {
  const float* out0   = (const float*)d_in[0];
  const float* out1   = (const float*)d_in[1];
  const int*   labels = (const int*)d_in[2];
  float*       out    = (float*)d_out;

  char* ws = (char*)d_ws;
  unsigned char* n0 = (unsigned char*)ws;                            // 4 MB
  unsigned char* n1 = (unsigned char*)(ws + (size_t)N * D);          // 4 MB
  float* part_pos = (float*)(ws + (size_t)2 * N * D);                // 2 MB
  float* part_all = part_pos + (size_t)CGROUPS * N;                  // 2 MB
  float* blocksum = part_all + (size_t)CGROUPS * N;                  // 128 B

  hipLaunchKernelGGL(normalize_kernel, dim3(2 * N / 4), dim3(256), 0, stream,
                     out0, out1, n0, n1);
  hipLaunchKernelGGL(ntxent_main, dim3(4096), dim3(256), 0, stream,
                     n0, n1, labels, part_pos, part_all);
  hipLaunchKernelGGL(row_reduce, dim3(N / 256), dim3(256), 0, stream,
                     part_pos, part_all, blocksum);
  hipLaunchKernelGGL(final_sum, dim3(1), dim3(64), 0, stream,
                     blocksum, out);
}